// Round 4
// baseline (180.032 us; speedup 1.0000x reference)
//
#include <hip/hip_runtime.h>

// BeBertEmbedding: out[b,s,d] = pe[s,d]
//                             + (input_ids[b,s]==0 ? W_tok[d,0]+b_tok[d] : 0)
//                             + (segment[b,s]==0   ? W_seg[d,0]+b_seg[d] : 0)
// The reference's where() keeps the gathered embedding ONLY for pad tokens
// (id==0), for which the gathered column is always column 0. Non-pad tokens
// get the constant float(padding_idx)=0.0 vector. So no vocab gather needed.
//
// R1: one block per s; pe read once; NT stores (out is write-once).
// R4: fuse the W[:,0]+b fold into the embed kernel — each thread loads its
// own 4 strided W words (768 cache lines total, L2-resident after warmup).
// Removes the second launch + graph dependency (~6-12 us of a ~25 us
// controllable window; the other ~150 us of dur_us is harness poison/restore
// traffic we cannot touch).

#define VOCAB 32000
#define DMODEL 768
#define SEQ 2048
#define NB 16
#define D4 (DMODEL / 4)  // 192 float4 per row

typedef float f4 __attribute__((ext_vector_type(4)));

// One block per s in [0,SEQ); 192 threads; each thread owns one float4 lane
// of the embedding row and stores it for all NB batches.
__global__ __launch_bounds__(192) void embed_kernel(
        const int* __restrict__ ids,     // [NB, SEQ]
        const int* __restrict__ segs,    // [NB, SEQ]
        const float* __restrict__ W_tok, // [DMODEL, VOCAB]
        const float* __restrict__ b_tok, // [DMODEL]
        const float* __restrict__ W_seg, // [DMODEL, 3]
        const float* __restrict__ b_seg, // [DMODEL]
        const float* __restrict__ pe,    // [SEQ, DMODEL]
        float* __restrict__ out) {       // [NB, SEQ, DMODEL]
    const int s  = blockIdx.x;
    const int d4 = threadIdx.x;
    const int d  = d4 * 4;

    // Fold W[:,0]+b in-register. Strided loads: 4 distinct cache lines per
    // thread, 768 lines total across the grid -> L2 hits after first blocks.
    f4 vt, vg;
#pragma unroll
    for (int j = 0; j < 4; ++j) {
        vt[j] = W_tok[(size_t)(d + j) * VOCAB] + b_tok[d + j];
        vg[j] = W_seg[(d + j) * 3] + b_seg[d + j];
    }

    const f4 p = ((const f4*)pe)[s * D4 + d4];
    const f4 zero = {0.0f, 0.0f, 0.0f, 0.0f};

    // Preload all batch flags (same address across the block -> broadcast).
    bool t[NB], g[NB];
#pragma unroll
    for (int b = 0; b < NB; ++b) {
        t[b] = (ids[b * SEQ + s] == 0);
        g[b] = (segs[b * SEQ + s] == 0);
    }

    f4* o4 = (f4*)out;
#pragma unroll
    for (int b = 0; b < NB; ++b) {
        // Match reference fp add order: (tok + pe) + seg
        f4 o = ((t[b] ? vt : zero) + p) + (g[b] ? vg : zero);
        __builtin_nontemporal_store(o, &o4[((size_t)b * SEQ + s) * D4 + d4]);
    }
}

extern "C" void kernel_launch(void* const* d_in, const int* in_sizes, int n_in,
                              void* d_out, int out_size, void* d_ws, size_t ws_size,
                              hipStream_t stream) {
    const int*   ids   = (const int*)d_in[0];
    const int*   segs  = (const int*)d_in[1];
    const float* W_tok = (const float*)d_in[2];
    const float* b_tok = (const float*)d_in[3];
    const float* W_seg = (const float*)d_in[4];
    const float* b_seg = (const float*)d_in[5];
    const float* pe    = (const float*)d_in[6];
    float* out = (float*)d_out;

    embed_kernel<<<SEQ, 192, 0, stream>>>(ids, segs, W_tok, b_tok, W_seg,
                                          b_seg, pe, out);
}